// Round 19
// baseline (786.637 us; speedup 1.0000x reference)
//
#include <hip/hip_runtime.h>

#define NCH    8
#define NBASIS 30
#define NXS    256
#define NF     200
#define NX     (NXS*NXS*2)      // 131072
#define NIMG   (NCH*NBASIS)     // 240
#define NFT    13               // f-tiles of 16 (13*16 = 208 >= 200)

typedef float    f32x4  __attribute__((ext_vector_type(4)));
typedef unsigned u32x4  __attribute__((ext_vector_type(4)));
typedef short    bf16x8 __attribute__((ext_vector_type(8)));

__device__ __forceinline__ int bitrev8(int v) {
    return (int)(__builtin_bitreverse32((unsigned)v) >> 24);
}

__device__ __forceinline__ unsigned short f2bf(float f) {   // RNE f32->bf16
    unsigned u = __float_as_uint(f);
    return (unsigned short)((u + 0x7FFFu + ((u >> 16) & 1u)) >> 16);
}

// ---------------------------------------------------------------------------
// Pass 1: w = (x * csm) * (-1)^(row+col); FFT along the contiguous (col) axis.
// Output bf16 (Amid).
// ---------------------------------------------------------------------------
__global__ __launch_bounds__(256) void fft_rows_kernel(
        const float* __restrict__ x, const float* __restrict__ csm,
        unsigned short* __restrict__ Amid) {
    __shared__ float ldsRe[4][256];
    __shared__ float ldsIm[4][256];
    __shared__ float twRe[128], twIm[128];

    const int tid   = threadIdx.x;
    const int slice = tid >> 6;
    const int lane  = tid & 63;
    const int blk   = blockIdx.x;       // m*64 + rowTile
    const int m     = blk >> 6;
    const int row   = ((blk & 63) << 2) + slice;
    const int c     = m / NBASIS;
    const int b     = m - c * NBASIS;

    if (tid < 128) {
        float a = (float)tid * (1.0f / 128.0f);   // theta = pi * a
        twRe[tid] =  cospif(a);
        twIm[tid] = -sinpif(a);
    }

    const float* xr = x   + ((size_t)(b * NXS + row) * NXS) * 2;
    const float* cr = csm + ((size_t)(c * NXS + row) * NXS) * 2;
    #pragma unroll
    for (int j = 0; j < 4; ++j) {
        int col = lane + 64 * j;
        float2 xv = *(const float2*)(xr + col * 2);
        float2 cv = *(const float2*)(cr + col * 2);
        float s = ((row + col) & 1) ? -1.0f : 1.0f;
        ldsRe[slice][col] = s * (xv.x * cv.x - xv.y * cv.y);
        ldsIm[slice][col] = s * (xv.x * cv.y + xv.y * cv.x);
    }
    __syncthreads();

    #pragma unroll
    for (int half = 128; half >= 1; half >>= 1) {
        #pragma unroll
        for (int qq = 0; qq < 2; ++qq) {
            int q  = lane + 64 * qq;
            int g  = q / half;
            int j  = q - g * half;
            int i0 = g * 2 * half + j;
            int i1 = i0 + half;
            float ar = ldsRe[slice][i0], ai = ldsIm[slice][i0];
            float br = ldsRe[slice][i1], bi = ldsIm[slice][i1];
            ldsRe[slice][i0] = ar + br;
            ldsIm[slice][i0] = ai + bi;
            float dr = ar - br, di = ai - bi;
            int k = j * (128 / half);
            float wr = twRe[k], wi = twIm[k];
            ldsRe[slice][i1] = dr * wr - di * wi;
            ldsIm[slice][i1] = dr * wi + di * wr;
        }
        __syncthreads();
    }

    unsigned short* outp = Amid + (size_t)m * NX + (size_t)row * NXS * 2;
    #pragma unroll
    for (int j = 0; j < 4; ++j) {
        int k  = lane + 64 * j;
        int rk = bitrev8(k);
        unsigned pack = (unsigned)f2bf(ldsRe[slice][rk])
                      | ((unsigned)f2bf(ldsIm[slice][rk]) << 16);
        *(unsigned*)(outp + k * 2) = pack;
    }
}

// ---------------------------------------------------------------------------
// Pass 2: FFT along the row axis; bf16 in (Amid), bf16 out (Abf).
// ---------------------------------------------------------------------------
#define CTILE 16
__global__ __launch_bounds__(256) void fft_cols_kernel(
        const unsigned short* __restrict__ Amid, unsigned short* __restrict__ Abf) {
    __shared__ float ldsRe[CTILE][257];
    __shared__ float ldsIm[CTILE][257];
    __shared__ float twRe[128], twIm[128];

    const int tid = threadIdx.x;
    const int blk = blockIdx.x;
    const int m   = blk >> 4;             // 16 tiles per image
    const int k0  = (blk & 15) * CTILE;

    if (tid < 128) {
        float a = (float)tid * (1.0f / 128.0f);
        twRe[tid] =  cospif(a);
        twIm[tid] = -sinpif(a);
    }

    const unsigned short* base = Amid + (size_t)m * NX;
    #pragma unroll
    for (int it = 0; it < 16; ++it) {
        int li = it * 256 + tid;
        int r  = li >> 4;
        int cc = li & 15;
        unsigned v = *(const unsigned*)(base + ((size_t)r * NXS + k0 + cc) * 2);
        ldsRe[cc][r] = __uint_as_float(v << 16);
        ldsIm[cc][r] = __uint_as_float(v & 0xFFFF0000u);
    }
    __syncthreads();

    const int slice = tid >> 6;
    const int lane  = tid & 63;

    #pragma unroll
    for (int half = 128; half >= 1; half >>= 1) {
        #pragma unroll
        for (int ci = 0; ci < 4; ++ci) {
            int col = slice * 4 + ci;
            #pragma unroll
            for (int qq = 0; qq < 2; ++qq) {
                int q  = lane + 64 * qq;
                int g  = q / half;
                int j  = q - g * half;
                int i0 = g * 2 * half + j;
                int i1 = i0 + half;
                float ar = ldsRe[col][i0], ai = ldsIm[col][i0];
                float br = ldsRe[col][i1], bi = ldsIm[col][i1];
                ldsRe[col][i0] = ar + br;
                ldsIm[col][i0] = ai + bi;
                float dr = ar - br, di = ai - bi;
                int k = j * (128 / half);
                float wr = twRe[k], wi = twIm[k];
                ldsRe[col][i1] = dr * wr - di * wi;
                ldsIm[col][i1] = dr * wi + di * wr;
            }
        }
        __syncthreads();
    }

    unsigned short* obase = Abf + (size_t)m * NX;
    #pragma unroll
    for (int it = 0; it < 16; ++it) {
        int li = it * 256 + tid;
        int ky = li >> 4;
        int cc = li & 15;
        int kx = k0 + cc;
        int rk = bitrev8(ky);
        float s = (((ky + kx) & 1) ? -1.0f : 1.0f) * (1.0f / 256.0f);
        unsigned pack = ((unsigned)f2bf(s * ldsIm[cc][rk]) << 16)
                      |  (unsigned)f2bf(s * ldsRe[cc][rk]);
        *(unsigned*)(obase + ((size_t)ky * NXS + kx) * 2) = pack;
    }
}

// ---------------------------------------------------------------------------
// VT -> fragment-ordered bf16 (k=(lane>>4)*8+j, f=lane&15, zero-padded).
// ---------------------------------------------------------------------------
__global__ __launch_bounds__(256) void vt_prep_kernel(
        const float* __restrict__ VT, unsigned short* __restrict__ VTfrag) {
    int i = blockIdx.x * 256 + threadIdx.x;
    if (i >= NFT * 512) return;
    int ft = i >> 9, r = i & 511, lane = r >> 3, j = r & 7;
    int k = (lane >> 4) * 8 + j;
    int f = ft * 16 + (lane & 15);
    unsigned short v = 0;
    if (k < NBASIS && f < NF) v = f2bf(VT[k * NF + f]);
    VTfrag[i] = v;
}

// ---------------------------------------------------------------------------
// Stage 3, 1024-n blocks. R18: NT >> normal (confirmed); all instruction-level
// store theories dead. Surviving theory: DRAM page granularity — R16 blocks
// write only 1 KB per (c,f) row, adjacent chunks come from unsynchronized
// blocks -> every 1 KB pays a row activation. This version: block = 1024 n,
// wave = 256 n x 16 f per ft (16 MFMAs, yfrag[16]); per-ft raw s_barrier
// aligns the 4 waves so the block emits 16 f-rows x 4 KB CONTIGUOUS in one
// window. CPB=1. Zero VMEM loads in the store stream (R15 invariant): VT in
// 52 VGPRs, mask in 26 bit-packed VGPRs (ft loop fully unrolled -> static
// indices), Y staged per-wave. LDS: per-wave 16 KB region, ylds (bf16
// [32][256]) union ldsW (f32 [16][256]), XOR-swizzled (16B-block idx ^=
// row-derived) -> all b128 LDS ops at the 8-cycle optimum. 64 KB total ->
// 2 blocks/CU; waves_per_eu(2,2) keeps the ~190-reg live set resident.
// ---------------------------------------------------------------------------
__global__ __launch_bounds__(256)
__attribute__((amdgpu_waves_per_eu(2, 2)))
void project_mfma_kernel(
        const unsigned short* __restrict__ Abf,    // [240][NX] bf16
        const unsigned short* __restrict__ VTfrag, // [13][64][8] bf16
        const void*           __restrict__ maskT,  // [200][NX] byte or int32
        float* __restrict__ out) {
    __shared__ __align__(16) unsigned char smem[4][16384];   // 65536 B

    const int tid  = threadIdx.x;
    const int wv   = tid >> 6;
    const int lane = tid & 63;
    const int ksec = lane >> 4;
    const int fr   = lane & 15;
    const int c    = blockIdx.y;
    const int n0w  = blockIdx.x * 1024 + wv * 256;   // wave's 256-n strip

    unsigned char* myLds = smem[wv];

    // --- VT fragments into registers (13 x bf16x8 = 52 VGPR), L2-hot. ---
    bf16x8 vtreg[NFT];
    #pragma unroll
    for (int ft = 0; ft < NFT; ++ft)
        vtreg[ft] = *(const bf16x8*)(VTfrag + ft * 512 + lane * 8);

    // --- Mask dtype sniff (uniform scalar loads). ---
    const unsigned* mwd = (const unsigned*)maskT;
    bool byteMode = false;
    #pragma unroll
    for (int i = 0; i < 32; ++i) byteMode |= (mwd[i] > 1u);

    // --- Bit-pack mask: bit (fn&7)*4+r of mbits[ft*2+(fn>>3)], for
    //     f = ft*16+fr, n = n0w + fn*16 + ksec*4 + r. All before stores. ---
    unsigned mbits[NFT * 2];
    #pragma unroll
    for (int i = 0; i < NFT * 2; ++i) mbits[i] = 0u;
    if (byteMode) {
        const unsigned char* mb = (const unsigned char*)maskT + n0w + ksec * 4;
        #pragma unroll
        for (int ft = 0; ft < NFT; ++ft) {
            const int  f_l = ft * 16 + fr;
            const bool fok = f_l < NF;
            #pragma unroll
            for (int fn = 0; fn < 16; ++fn) {
                unsigned w = fok
                    ? *(const unsigned*)(mb + (size_t)f_l * NX + fn * 16) : 0u;
                unsigned nib = (w | (w >> 7) | (w >> 14) | (w >> 21)) & 0xFu;
                mbits[ft * 2 + (fn >> 3)] |= nib << ((fn & 7) * 4);
            }
        }
    } else {
        const int* mi = (const int*)maskT + n0w + ksec * 4;
        #pragma unroll
        for (int ft = 0; ft < NFT; ++ft) {
            const int  f_l = ft * 16 + fr;
            const bool fok = f_l < NF;
            #pragma unroll
            for (int fn = 0; fn < 16; ++fn) {
                unsigned nib = 0u;
                if (fok) {
                    u32x4 v = *(const u32x4*)(mi + (size_t)f_l * NX + fn * 16);
                    nib = (v.x ? 1u : 0u) | (v.y ? 2u : 0u)
                        | (v.z ? 4u : 0u) | (v.w ? 8u : 0u);
                }
                mbits[ft * 2 + (fn >> 3)] |= nib << ((fn & 7) * 4);
            }
        }
    }

    // --- Stage Y strip (30 rows x 256 n bf16) into swizzled ylds. ---
    {
        const unsigned short* src = Abf + (size_t)c * NBASIS * NX + n0w;
        #pragma unroll
        for (int i = 0; i < 15; ++i) {
            int flat = i * 64 + lane;            // 0..959
            int row  = flat >> 5, seg = flat & 31;
            u32x4 v = *(const u32x4*)(src + (size_t)row * NX + seg * 8);
            int blk = (seg ^ (row & 7) ^ ((row >> 3) << 2)) & 31;
            *(u32x4*)(myLds + row * 512 + blk * 16) = v;
        }
        // zero K-pad rows 30,31
        int row = 30 + (lane >> 5), seg = lane & 31;
        int blk = (seg ^ (row & 7) ^ ((row >> 3) << 2)) & 31;
        *(u32x4*)(myLds + row * 512 + blk * 16) = (u32x4)(0u, 0u, 0u, 0u);
    }
    asm volatile("s_waitcnt lgkmcnt(0)" ::: "memory");
    __builtin_amdgcn_sched_barrier(0);

    // --- Gather 16 A-frags: yfrag[fn][j] = Y[k=ksec*8+j][n_local=fn*16+fr]. ---
    bf16x8 yfrag[16];
    #pragma unroll
    for (int fn = 0; fn < 16; ++fn) {
        #pragma unroll
        for (int j = 0; j < 8; ++j) {
            int col = fn * 16 + fr;
            int row = ksec * 8 + j;
            int blk = ((col >> 3) ^ j ^ (ksec << 2)) & 31;
            unsigned short v = *(const unsigned short*)
                (myLds + row * 512 + blk * 16 + (col & 7) * 2);
            yfrag[fn][j] = (short)v;
        }
    }
    asm volatile("s_waitcnt lgkmcnt(0)" ::: "memory");
    __builtin_amdgcn_sched_barrier(0);       // ylds dead; region becomes ldsW

    float* outc = out + (size_t)c * NF * NX;

    #pragma unroll
    for (int ft = 0; ft < NFT; ++ft) {
        __builtin_amdgcn_s_barrier();        // align waves: 4 KB rows together

        bf16x8 vt = vtreg[ft];
        #pragma unroll
        for (int fn = 0; fn < 16; ++fn) {
            unsigned nib = (mbits[ft * 2 + (fn >> 3)] >> ((fn & 7) * 4)) & 0xFu;
            f32x4 d = __builtin_amdgcn_mfma_f32_16x16x32_bf16(
                yfrag[fn], vt, (f32x4)(0.f, 0.f, 0.f, 0.f), 0, 0, 0);
            f32x4 o;
            #pragma unroll
            for (int r = 0; r < 4; ++r)
                o[r] = (nib & (1u << r)) ? d[r] : 0.0f;
            int blkw = ((fn * 4 + ksec) ^ (fr & 7)) & 63;
            *(f32x4*)(myLds + fr * 1024 + blkw * 16) = o;
        }
        asm volatile("s_waitcnt lgkmcnt(0)" ::: "memory");
        __builtin_amdgcn_sched_barrier(0);
        __builtin_amdgcn_wave_barrier();

        // Drain: 16 stores x (64 lanes x 16 B) = 1 KB contiguous per f-row
        // per wave; block's 4 waves cover 4 KB of each f-row in this window.
        #pragma unroll
        for (int fl = 0; fl < 16; ++fl) {
            int f = ft * 16 + fl;
            if (f < NF) {
                int blkr = (lane ^ (fl & 7)) & 63;
                f32x4 v = *(const f32x4*)(myLds + fl * 1024 + blkr * 16);
                __builtin_nontemporal_store(v,
                    (f32x4*)(outc + (size_t)f * NX + n0w + lane * 4));
            }
        }
        asm volatile("s_waitcnt lgkmcnt(0)" ::: "memory");
        __builtin_amdgcn_sched_barrier(0);
        __builtin_amdgcn_wave_barrier();
    }
}

extern "C" void kernel_launch(void* const* d_in, const int* in_sizes, int n_in,
                              void* d_out, int out_size, void* d_ws, size_t ws_size,
                              hipStream_t stream) {
    const float* x    = (const float*)d_in[0];   // (30,256,256,2) f32
    const float* csm  = (const float*)d_in[1];   // (8,256,256,2) f32
    const float* VT   = (const float*)d_in[2];   // (30,200) f32
    const void*  mask = d_in[3];                 // (200,131072) bool/int
    float* out = (float*)d_out;                  // (8,200,131072) f32

    char* ws = (char*)d_ws;
    unsigned short* Amid   = (unsigned short*)ws;                         // 62.9 MB
    unsigned short* Abf    = (unsigned short*)(ws + ((size_t)64 << 20));  // 62.9 MB
    unsigned short* VTfrag = (unsigned short*)(ws + ((size_t)128 << 20)); // 13.3 KB

    vt_prep_kernel<<<(NFT * 512 + 255) / 256, 256, 0, stream>>>(VT, VTfrag);
    fft_rows_kernel<<<NIMG * 64, 256, 0, stream>>>(x, csm, Amid);
    fft_cols_kernel<<<NIMG * 16, 256, 0, stream>>>(Amid, Abf);
    project_mfma_kernel<<<dim3(NX / 1024, NCH), 256, 0, stream>>>(
        Abf, VTfrag, mask, out);
}

// Round 20
// 333.303 us; speedup vs baseline: 2.3601x; 2.3601x over previous
//
#include <hip/hip_runtime.h>

#define NCH    8
#define NBASIS 30
#define NXS    256
#define NF     200
#define NX     (NXS*NXS*2)      // 131072
#define NIMG   (NCH*NBASIS)     // 240
#define NFT    13               // f-tiles of 16 (13*16 = 208 >= 200)
#define CPB    4                // channels per block (stage-3)

typedef float    f32x4  __attribute__((ext_vector_type(4)));
typedef unsigned u32x4  __attribute__((ext_vector_type(4)));
typedef short    bf16x8 __attribute__((ext_vector_type(8)));

__device__ __forceinline__ int bitrev8(int v) {
    return (int)(__builtin_bitreverse32((unsigned)v) >> 24);
}

__device__ __forceinline__ unsigned short f2bf(float f) {   // RNE f32->bf16
    unsigned u = __float_as_uint(f);
    return (unsigned short)((u + 0x7FFFu + ((u >> 16) & 1u)) >> 16);
}

// ---------------------------------------------------------------------------
// Pass 1: w = (x * csm) * (-1)^(row+col); FFT along the contiguous (col) axis.
// Output bf16 (Amid).
// ---------------------------------------------------------------------------
__global__ __launch_bounds__(256) void fft_rows_kernel(
        const float* __restrict__ x, const float* __restrict__ csm,
        unsigned short* __restrict__ Amid) {
    __shared__ float ldsRe[4][256];
    __shared__ float ldsIm[4][256];
    __shared__ float twRe[128], twIm[128];

    const int tid   = threadIdx.x;
    const int slice = tid >> 6;
    const int lane  = tid & 63;
    const int blk   = blockIdx.x;       // m*64 + rowTile
    const int m     = blk >> 6;
    const int row   = ((blk & 63) << 2) + slice;
    const int c     = m / NBASIS;
    const int b     = m - c * NBASIS;

    if (tid < 128) {
        float a = (float)tid * (1.0f / 128.0f);   // theta = pi * a
        twRe[tid] =  cospif(a);
        twIm[tid] = -sinpif(a);
    }

    const float* xr = x   + ((size_t)(b * NXS + row) * NXS) * 2;
    const float* cr = csm + ((size_t)(c * NXS + row) * NXS) * 2;
    #pragma unroll
    for (int j = 0; j < 4; ++j) {
        int col = lane + 64 * j;
        float2 xv = *(const float2*)(xr + col * 2);
        float2 cv = *(const float2*)(cr + col * 2);
        float s = ((row + col) & 1) ? -1.0f : 1.0f;
        ldsRe[slice][col] = s * (xv.x * cv.x - xv.y * cv.y);
        ldsIm[slice][col] = s * (xv.x * cv.y + xv.y * cv.x);
    }
    __syncthreads();

    #pragma unroll
    for (int half = 128; half >= 1; half >>= 1) {
        #pragma unroll
        for (int qq = 0; qq < 2; ++qq) {
            int q  = lane + 64 * qq;
            int g  = q / half;
            int j  = q - g * half;
            int i0 = g * 2 * half + j;
            int i1 = i0 + half;
            float ar = ldsRe[slice][i0], ai = ldsIm[slice][i0];
            float br = ldsRe[slice][i1], bi = ldsIm[slice][i1];
            ldsRe[slice][i0] = ar + br;
            ldsIm[slice][i0] = ai + bi;
            float dr = ar - br, di = ai - bi;
            int k = j * (128 / half);
            float wr = twRe[k], wi = twIm[k];
            ldsRe[slice][i1] = dr * wr - di * wi;
            ldsIm[slice][i1] = dr * wi + di * wr;
        }
        __syncthreads();
    }

    unsigned short* outp = Amid + (size_t)m * NX + (size_t)row * NXS * 2;
    #pragma unroll
    for (int j = 0; j < 4; ++j) {
        int k  = lane + 64 * j;
        int rk = bitrev8(k);
        unsigned pack = (unsigned)f2bf(ldsRe[slice][rk])
                      | ((unsigned)f2bf(ldsIm[slice][rk]) << 16);
        *(unsigned*)(outp + k * 2) = pack;
    }
}

// ---------------------------------------------------------------------------
// Pass 2: FFT along the row axis; bf16 in (Amid), bf16 out (Abf).
// ---------------------------------------------------------------------------
#define CTILE 16
__global__ __launch_bounds__(256) void fft_cols_kernel(
        const unsigned short* __restrict__ Amid, unsigned short* __restrict__ Abf) {
    __shared__ float ldsRe[CTILE][257];
    __shared__ float ldsIm[CTILE][257];
    __shared__ float twRe[128], twIm[128];

    const int tid = threadIdx.x;
    const int blk = blockIdx.x;
    const int m   = blk >> 4;             // 16 tiles per image
    const int k0  = (blk & 15) * CTILE;

    if (tid < 128) {
        float a = (float)tid * (1.0f / 128.0f);
        twRe[tid] =  cospif(a);
        twIm[tid] = -sinpif(a);
    }

    const unsigned short* base = Amid + (size_t)m * NX;
    #pragma unroll
    for (int it = 0; it < 16; ++it) {
        int li = it * 256 + tid;
        int r  = li >> 4;
        int cc = li & 15;
        unsigned v = *(const unsigned*)(base + ((size_t)r * NXS + k0 + cc) * 2);
        ldsRe[cc][r] = __uint_as_float(v << 16);
        ldsIm[cc][r] = __uint_as_float(v & 0xFFFF0000u);
    }
    __syncthreads();

    const int slice = tid >> 6;
    const int lane  = tid & 63;

    #pragma unroll
    for (int half = 128; half >= 1; half >>= 1) {
        #pragma unroll
        for (int ci = 0; ci < 4; ++ci) {
            int col = slice * 4 + ci;
            #pragma unroll
            for (int qq = 0; qq < 2; ++qq) {
                int q  = lane + 64 * qq;
                int g  = q / half;
                int j  = q - g * half;
                int i0 = g * 2 * half + j;
                int i1 = i0 + half;
                float ar = ldsRe[col][i0], ai = ldsIm[col][i0];
                float br = ldsRe[col][i1], bi = ldsIm[col][i1];
                ldsRe[col][i0] = ar + br;
                ldsIm[col][i0] = ai + bi;
                float dr = ar - br, di = ai - bi;
                int k = j * (128 / half);
                float wr = twRe[k], wi = twIm[k];
                ldsRe[col][i1] = dr * wr - di * wi;
                ldsIm[col][i1] = dr * wi + di * wr;
            }
        }
        __syncthreads();
    }

    unsigned short* obase = Abf + (size_t)m * NX;
    #pragma unroll
    for (int it = 0; it < 16; ++it) {
        int li = it * 256 + tid;
        int ky = li >> 4;
        int cc = li & 15;
        int kx = k0 + cc;
        int rk = bitrev8(ky);
        float s = (((ky + kx) & 1) ? -1.0f : 1.0f) * (1.0f / 256.0f);
        unsigned pack = ((unsigned)f2bf(s * ldsIm[cc][rk]) << 16)
                      |  (unsigned)f2bf(s * ldsRe[cc][rk]);
        *(unsigned*)(obase + ((size_t)ky * NXS + kx) * 2) = pack;
    }
}

// ---------------------------------------------------------------------------
// VT -> fragment-ordered bf16 (k=(lane>>4)*8+j, f=lane&15, zero-padded).
// ---------------------------------------------------------------------------
__global__ __launch_bounds__(256) void vt_prep_kernel(
        const float* __restrict__ VT, unsigned short* __restrict__ VTfrag) {
    int i = blockIdx.x * 256 + threadIdx.x;
    if (i >= NFT * 512) return;
    int ft = i >> 9, r = i & 511, lane = r >> 3, j = r & 7;
    int k = (lane >> 4) * 8 + j;
    int f = ft * 16 + (lane & 15);
    unsigned short v = 0;
    if (k < NBASIS && f < NF) v = f2bf(VT[k * NF + f]);
    VTfrag[i] = v;
}

// ---------------------------------------------------------------------------
// Stage 3. R19 post-mortem: 1024-n blocks spilled (VGPR 128 < ~190 live,
// WRITE_SIZE +76%) -> reverted to R16 (proven 326 us). One clean fix kept:
// R16's mask bit-pack loads were 16-way scattered per instruction (16 f-rows
// 128 KB apart, 16 B used per 128 B line -> ~8x line amplification + long
// divergent gather chain at block start). Now: each wave loads mask f-rows
// COALESCED (64 lanes x 4 B contiguous), converts to per-f 256-bit occupancy
// via 4 __ballot's, parks in a 6.7 KB LDS bit-matrix; threads extract their
// mbits via a few ds_reads. All before the store stream (R15 invariant:
// zero VMEM loads inside the NT-store stream). LDS 39.4 KB -> 4 blocks/CU.
// ---------------------------------------------------------------------------
__global__ __launch_bounds__(256) void project_mfma_kernel(
        const unsigned short* __restrict__ Abf,    // [240][NX] bf16
        const unsigned short* __restrict__ VTfrag, // [13][64][8] bf16
        const void*           __restrict__ maskT,  // [200][NX] byte or int32
        float* __restrict__ out) {
    __shared__ __align__(16) unsigned char smem[4][4864];      // 19456 B
    __shared__ __align__(16) unsigned short vtlds[NFT * 512];  // 13312 B
    __shared__ unsigned long long mbuf[NFT * 16][4];           // 6656 B

    const int tid  = threadIdx.x;
    const int wv   = tid >> 6;
    const int lane = tid & 63;
    const int ksec = lane >> 4;
    const int fr   = lane & 15;
    const int c0   = blockIdx.y * CPB;
    const int n0b  = blockIdx.x * 256;
    const int n0w  = n0b + wv * 64;

    // Copy VTfrag to LDS.
    {
        const u32x4* src = (const u32x4*)VTfrag;
        u32x4*       dst = (u32x4*)vtlds;
        for (int i = tid; i < NFT * 512 / 8; i += 256) dst[i] = src[i];
    }

    // Detect mask storage: bool-as-byte vs int32 (uniform, scalar loads).
    const unsigned* mwd = (const unsigned*)maskT;
    bool byteMode = false;
    #pragma unroll
    for (int i = 0; i < 32; ++i) byteMode |= (mwd[i] > 1u);

    // --- Coalesced mask staging: wave wv handles f = i*4 + wv. Lane l loads
    //     the 4 mask values at n = n0b + 4l + {0..3} (contiguous 256 B or
    //     1 KB per wave-instr), ballots them into 4 x 64-bit occupancy words
    //     (bit l of word r = mask[f][n0b+4l+r]), lanes 0..3 park them in mbuf.
    if (byteMode) {
        const unsigned char* mb = (const unsigned char*)maskT;
        #pragma unroll 4
        for (int i = 0; i < 52; ++i) {
            int f = i * 4 + wv;         // < 208
            unsigned w = 0u;
            if (f < NF)
                w = *(const unsigned*)(mb + (size_t)f * NX + n0b + lane * 4);
            unsigned long long B0 = __ballot((w & 0x000000FFu) != 0u);
            unsigned long long B1 = __ballot((w & 0x0000FF00u) != 0u);
            unsigned long long B2 = __ballot((w & 0x00FF0000u) != 0u);
            unsigned long long B3 = __ballot((w & 0xFF000000u) != 0u);
            if (lane < 4) {
                unsigned long long B = (lane == 0) ? B0 : (lane == 1) ? B1
                                     : (lane == 2) ? B2 : B3;
                mbuf[f][lane] = B;
            }
        }
    } else {
        const int* mi = (const int*)maskT;
        #pragma unroll 4
        for (int i = 0; i < 52; ++i) {
            int f = i * 4 + wv;
            u32x4 v = (u32x4)(0u, 0u, 0u, 0u);
            if (f < NF)
                v = *(const u32x4*)(mi + (size_t)f * NX + n0b + lane * 4);
            unsigned long long B0 = __ballot(v.x != 0u);
            unsigned long long B1 = __ballot(v.y != 0u);
            unsigned long long B2 = __ballot(v.z != 0u);
            unsigned long long B3 = __ballot(v.w != 0u);
            if (lane < 4) {
                unsigned long long B = (lane == 0) ? B0 : (lane == 1) ? B1
                                     : (lane == 2) ? B2 : B3;
                mbuf[f][lane] = B;
            }
        }
    }

    unsigned short (*ylds)[72] = (unsigned short (*)[72])smem[wv]; // 32x72 bf16
    float          (*ldsW)[68] = (float (*)[68])smem[wv];          // 16x68 f32

    // Prologue: load channel c0's Y strip into registers (before any store).
    u32x4 ycur[4];
    {
        const unsigned short* src = Abf + (size_t)c0 * NBASIS * NX + n0w;
        #pragma unroll
        for (int i = 0; i < 4; ++i) {
            int idx = lane + 64 * i;             // 0..255
            int row = idx >> 3, seg = idx & 7;
            ycur[i] = (u32x4)(0u, 0u, 0u, 0u);
            if (row < NBASIS)
                ycur[i] = *(const u32x4*)(src + (size_t)row * NX + seg * 8);
        }
    }

    __syncthreads();     // vtlds + mbuf ready

    // --- Extract this thread's mask bits from mbuf (LDS reads, pre-store). ---
    unsigned mbits[7] = {0u, 0u, 0u, 0u, 0u, 0u, 0u};
    #pragma unroll
    for (int ft = 0; ft < NFT; ++ft) {
        const int f_l = ft * 16 + fr;       // < 208; rows >= NF hold zeros
        unsigned long long B0 = mbuf[f_l][0], B1 = mbuf[f_l][1];
        unsigned long long B2 = mbuf[f_l][2], B3 = mbuf[f_l][3];
        #pragma unroll
        for (int fn = 0; fn < 4; ++fn) {
            int l = wv * 16 + fn * 4 + ksec;  // dword index within 256-n window
            unsigned nib = (unsigned)((B0 >> l) & 1ull)
                         | ((unsigned)((B1 >> l) & 1ull) << 1)
                         | ((unsigned)((B2 >> l) & 1ull) << 2)
                         | ((unsigned)((B3 >> l) & 1ull) << 3);
            const int p = ft * 16 + fn * 4;
            mbits[p >> 5] |= nib << (p & 31);
        }
    }

    #pragma unroll 1
    for (int cc = 0; cc < CPB; ++cc) {
        const int c = c0 + cc;

        // Write staged Y regs to LDS (DS in-order; compiler keeps may-alias order).
        #pragma unroll
        for (int i = 0; i < 4; ++i) {
            int idx = lane + 64 * i;
            int row = idx >> 3, seg = idx & 7;
            *(u32x4*)&ylds[row][seg * 8] = ycur[i];
        }

        // Gather A-frags: yfrag[fn][j] = Y[k=ksec*8+j][n_local=fn*16+fr].
        bf16x8 yfrag[4];
        #pragma unroll
        for (int fn = 0; fn < 4; ++fn) {
            #pragma unroll
            for (int j = 0; j < 8; ++j)
                yfrag[fn][j] = (short)ylds[ksec * 8 + j][fn * 16 + fr];
        }

        // Issue next channel's Y loads BEFORE this channel's store stream.
        if (cc + 1 < CPB) {
            const unsigned short* src = Abf + (size_t)(c + 1) * NBASIS * NX + n0w;
            #pragma unroll
            for (int i = 0; i < 4; ++i) {
                int idx = lane + 64 * i;
                int row = idx >> 3, seg = idx & 7;
                u32x4 v = (u32x4)(0u, 0u, 0u, 0u);
                if (row < NBASIS)
                    v = *(const u32x4*)(src + (size_t)row * NX + seg * 8);
                ycur[i] = v;
            }
        }

        float* outc = out + (size_t)c * NF * NX;

        #pragma unroll
        for (int ft = 0; ft < NFT; ++ft) {
            bf16x8 vt = *(const bf16x8*)&vtlds[ft * 512 + lane * 8]; // lgkm only

            #pragma unroll
            for (int fn = 0; fn < 4; ++fn) {
                const int p = ft * 16 + fn * 4;
                const unsigned nib = (mbits[p >> 5] >> (p & 31)) & 0xFu;
                f32x4 d = __builtin_amdgcn_mfma_f32_16x16x32_bf16(
                    yfrag[fn], vt, (f32x4)(0.f, 0.f, 0.f, 0.f), 0, 0, 0);
                f32x4 o;
                #pragma unroll
                for (int r = 0; r < 4; ++r)
                    o[r] = (nib & (1u << r)) ? d[r] : 0.0f;
                *(f32x4*)&ldsW[fr][fn * 16 + ksec * 4] = o;
            }

            // f-major drain: NT stores, 256 B contiguous per 16-lane group.
            #pragma unroll
            for (int rl = 0; rl < 4; ++rl) {
                int f_local = rl * 4 + ksec;
                int f = ft * 16 + f_local;
                f32x4 v = *(const f32x4*)&ldsW[f_local][fr * 4];
                if (f < NF)
                    __builtin_nontemporal_store(v,
                        (f32x4*)(outc + (size_t)f * NX + n0w + fr * 4));
            }
        }
    }
}

extern "C" void kernel_launch(void* const* d_in, const int* in_sizes, int n_in,
                              void* d_out, int out_size, void* d_ws, size_t ws_size,
                              hipStream_t stream) {
    const float* x    = (const float*)d_in[0];   // (30,256,256,2) f32
    const float* csm  = (const float*)d_in[1];   // (8,256,256,2) f32
    const float* VT   = (const float*)d_in[2];   // (30,200) f32
    const void*  mask = d_in[3];                 // (200,131072) bool/int
    float* out = (float*)d_out;                  // (8,200,131072) f32

    char* ws = (char*)d_ws;
    unsigned short* Amid   = (unsigned short*)ws;                         // 62.9 MB
    unsigned short* Abf    = (unsigned short*)(ws + ((size_t)64 << 20));  // 62.9 MB
    unsigned short* VTfrag = (unsigned short*)(ws + ((size_t)128 << 20)); // 13.3 KB

    vt_prep_kernel<<<(NFT * 512 + 255) / 256, 256, 0, stream>>>(VT, VTfrag);
    fft_rows_kernel<<<NIMG * 64, 256, 0, stream>>>(x, csm, Amid);
    fft_cols_kernel<<<NIMG * 16, 256, 0, stream>>>(Amid, Abf);
    project_mfma_kernel<<<dim3(NX / 256, NCH / CPB), 256, 0, stream>>>(
        Abf, VTfrag, mask, out);
}

// Round 21
// 324.617 us; speedup vs baseline: 2.4233x; 1.0268x over previous
//
#include <hip/hip_runtime.h>

#define NCH    8
#define NBASIS 30
#define NXS    256
#define NF     200
#define NX     (NXS*NXS*2)      // 131072
#define NIMG   (NCH*NBASIS)     // 240
#define NFT    13               // f-tiles of 16 (13*16 = 208 >= 200)
#define CPB    4                // channels per block (stage-3)

typedef float    f32x4  __attribute__((ext_vector_type(4)));
typedef unsigned u32x4  __attribute__((ext_vector_type(4)));
typedef short    bf16x8 __attribute__((ext_vector_type(8)));

__device__ __forceinline__ int bitrev8(int v) {
    return (int)(__builtin_bitreverse32((unsigned)v) >> 24);
}

__device__ __forceinline__ unsigned short f2bf(float f) {   // RNE f32->bf16
    unsigned u = __float_as_uint(f);
    return (unsigned short)((u + 0x7FFFu + ((u >> 16) & 1u)) >> 16);
}

// ---------------------------------------------------------------------------
// Pass 1: w = (x * csm) * (-1)^(row+col); FFT along the contiguous (col) axis.
// Output bf16 (Amid).
// ---------------------------------------------------------------------------
__global__ __launch_bounds__(256) void fft_rows_kernel(
        const float* __restrict__ x, const float* __restrict__ csm,
        unsigned short* __restrict__ Amid) {
    __shared__ float ldsRe[4][256];
    __shared__ float ldsIm[4][256];
    __shared__ float twRe[128], twIm[128];

    const int tid   = threadIdx.x;
    const int slice = tid >> 6;
    const int lane  = tid & 63;
    const int blk   = blockIdx.x;       // m*64 + rowTile
    const int m     = blk >> 6;
    const int row   = ((blk & 63) << 2) + slice;
    const int c     = m / NBASIS;
    const int b     = m - c * NBASIS;

    if (tid < 128) {
        float a = (float)tid * (1.0f / 128.0f);   // theta = pi * a
        twRe[tid] =  cospif(a);
        twIm[tid] = -sinpif(a);
    }

    const float* xr = x   + ((size_t)(b * NXS + row) * NXS) * 2;
    const float* cr = csm + ((size_t)(c * NXS + row) * NXS) * 2;
    #pragma unroll
    for (int j = 0; j < 4; ++j) {
        int col = lane + 64 * j;
        float2 xv = *(const float2*)(xr + col * 2);
        float2 cv = *(const float2*)(cr + col * 2);
        float s = ((row + col) & 1) ? -1.0f : 1.0f;
        ldsRe[slice][col] = s * (xv.x * cv.x - xv.y * cv.y);
        ldsIm[slice][col] = s * (xv.x * cv.y + xv.y * cv.x);
    }
    __syncthreads();

    #pragma unroll
    for (int half = 128; half >= 1; half >>= 1) {
        #pragma unroll
        for (int qq = 0; qq < 2; ++qq) {
            int q  = lane + 64 * qq;
            int g  = q / half;
            int j  = q - g * half;
            int i0 = g * 2 * half + j;
            int i1 = i0 + half;
            float ar = ldsRe[slice][i0], ai = ldsIm[slice][i0];
            float br = ldsRe[slice][i1], bi = ldsIm[slice][i1];
            ldsRe[slice][i0] = ar + br;
            ldsIm[slice][i0] = ai + bi;
            float dr = ar - br, di = ai - bi;
            int k = j * (128 / half);
            float wr = twRe[k], wi = twIm[k];
            ldsRe[slice][i1] = dr * wr - di * wi;
            ldsIm[slice][i1] = dr * wi + di * wr;
        }
        __syncthreads();
    }

    unsigned short* outp = Amid + (size_t)m * NX + (size_t)row * NXS * 2;
    #pragma unroll
    for (int j = 0; j < 4; ++j) {
        int k  = lane + 64 * j;
        int rk = bitrev8(k);
        unsigned pack = (unsigned)f2bf(ldsRe[slice][rk])
                      | ((unsigned)f2bf(ldsIm[slice][rk]) << 16);
        *(unsigned*)(outp + k * 2) = pack;
    }
}

// ---------------------------------------------------------------------------
// Pass 2: FFT along the row axis; bf16 in (Amid), bf16 out (Abf).
// ---------------------------------------------------------------------------
#define CTILE 16
__global__ __launch_bounds__(256) void fft_cols_kernel(
        const unsigned short* __restrict__ Amid, unsigned short* __restrict__ Abf) {
    __shared__ float ldsRe[CTILE][257];
    __shared__ float ldsIm[CTILE][257];
    __shared__ float twRe[128], twIm[128];

    const int tid = threadIdx.x;
    const int blk = blockIdx.x;
    const int m   = blk >> 4;             // 16 tiles per image
    const int k0  = (blk & 15) * CTILE;

    if (tid < 128) {
        float a = (float)tid * (1.0f / 128.0f);
        twRe[tid] =  cospif(a);
        twIm[tid] = -sinpif(a);
    }

    const unsigned short* base = Amid + (size_t)m * NX;
    #pragma unroll
    for (int it = 0; it < 16; ++it) {
        int li = it * 256 + tid;
        int r  = li >> 4;
        int cc = li & 15;
        unsigned v = *(const unsigned*)(base + ((size_t)r * NXS + k0 + cc) * 2);
        ldsRe[cc][r] = __uint_as_float(v << 16);
        ldsIm[cc][r] = __uint_as_float(v & 0xFFFF0000u);
    }
    __syncthreads();

    const int slice = tid >> 6;
    const int lane  = tid & 63;

    #pragma unroll
    for (int half = 128; half >= 1; half >>= 1) {
        #pragma unroll
        for (int ci = 0; ci < 4; ++ci) {
            int col = slice * 4 + ci;
            #pragma unroll
            for (int qq = 0; qq < 2; ++qq) {
                int q  = lane + 64 * qq;
                int g  = q / half;
                int j  = q - g * half;
                int i0 = g * 2 * half + j;
                int i1 = i0 + half;
                float ar = ldsRe[col][i0], ai = ldsIm[col][i0];
                float br = ldsRe[col][i1], bi = ldsIm[col][i1];
                ldsRe[col][i0] = ar + br;
                ldsIm[col][i0] = ai + bi;
                float dr = ar - br, di = ai - bi;
                int k = j * (128 / half);
                float wr = twRe[k], wi = twIm[k];
                ldsRe[col][i1] = dr * wr - di * wi;
                ldsIm[col][i1] = dr * wi + di * wr;
            }
        }
        __syncthreads();
    }

    unsigned short* obase = Abf + (size_t)m * NX;
    #pragma unroll
    for (int it = 0; it < 16; ++it) {
        int li = it * 256 + tid;
        int ky = li >> 4;
        int cc = li & 15;
        int kx = k0 + cc;
        int rk = bitrev8(ky);
        float s = (((ky + kx) & 1) ? -1.0f : 1.0f) * (1.0f / 256.0f);
        unsigned pack = ((unsigned)f2bf(s * ldsIm[cc][rk]) << 16)
                      |  (unsigned)f2bf(s * ldsRe[cc][rk]);
        *(unsigned*)(obase + ((size_t)ky * NXS + kx) * 2) = pack;
    }
}

// ---------------------------------------------------------------------------
// VT -> fragment-ordered bf16 (k=(lane>>4)*8+j, f=lane&15, zero-padded).
// ---------------------------------------------------------------------------
__global__ __launch_bounds__(256) void vt_prep_kernel(
        const float* __restrict__ VT, unsigned short* __restrict__ VTfrag) {
    int i = blockIdx.x * 256 + threadIdx.x;
    if (i >= NFT * 512) return;
    int ft = i >> 9, r = i & 511, lane = r >> 3, j = r & 7;
    int k = (lane >> 4) * 8 + j;
    int f = ft * 16 + (lane & 15);
    unsigned short v = 0;
    if (k < NBASIS && f < NF) v = f2bf(VT[k * NF + f]);
    VTfrag[i] = v;
}

// ---------------------------------------------------------------------------
// Stage 3 = R16 (proven 326 us) + XCD-aware n-chunk swizzle. R20 post-mortem:
// ballot mask staging neutral -> reverted. R19's 4KB-page test was spill-
// confounded, and the fills DO write >=4KB contiguous per block -> the page-
// concurrency theory was never actually tested. Here: same-XCD blocks
// (bid = k mod 8, round-robin dispatch) get ADJACENT 256-n chunks, so each
// XCD's ~32 concurrent blocks write 32 adjacent 1 KB chunks of every (c,f)
// row -> 4 KB pages covered by temporally-close same-XCD writes. One-line
// remap of bid -> n0b; everything else identical to R16.
// ---------------------------------------------------------------------------
__global__ __launch_bounds__(256) void project_mfma_kernel(
        const unsigned short* __restrict__ Abf,    // [240][NX] bf16
        const unsigned short* __restrict__ VTfrag, // [13][64][8] bf16
        const void*           __restrict__ maskT,  // [200][NX] byte or int32
        float* __restrict__ out) {
    __shared__ __align__(16) unsigned char smem[4][4864];      // 19456 B
    __shared__ __align__(16) unsigned short vtlds[NFT * 512];  // 13312 B

    const int tid  = threadIdx.x;
    const int wv   = tid >> 6;
    const int lane = tid & 63;
    const int ksec = lane >> 4;
    const int fr   = lane & 15;
    const int c0   = blockIdx.y * CPB;
    // XCD swizzle: XCD k (= bid%8) owns the contiguous chunk range
    // [k*64, (k+1)*64); successive same-XCD bids get adjacent chunks.
    const int bid  = blockIdx.x;                   // 0..511
    const int n0w  = ((bid & 7) * 64 + (bid >> 3)) * 256 + wv * 64;

    // Copy VTfrag to LDS (one block barrier, before any store).
    {
        const u32x4* src = (const u32x4*)VTfrag;
        u32x4*       dst = (u32x4*)vtlds;
        for (int i = tid; i < NFT * 512 / 8; i += 256) dst[i] = src[i];
    }

    // Detect mask storage: bool-as-byte vs int32 (uniform, scalar loads).
    const unsigned* mwd = (const unsigned*)maskT;
    bool byteMode = false;
    #pragma unroll
    for (int i = 0; i < 32; ++i) byteMode |= (mwd[i] > 1u);

    // Bit-pack this lane's mask: bit p = ft*16 + fn*4 + r  (f=ft*16+fr,
    // n = n0w + fn*16 + ksec*4 + r). All loads happen BEFORE any store.
    unsigned mbits[7] = {0u, 0u, 0u, 0u, 0u, 0u, 0u};
    if (byteMode) {
        const unsigned char* mb = (const unsigned char*)maskT + n0w + ksec * 4;
        #pragma unroll
        for (int ft = 0; ft < NFT; ++ft) {
            const int f_l = ft * 16 + fr;
            #pragma unroll
            for (int fn = 0; fn < 4; ++fn) {
                unsigned w = (f_l < NF)
                    ? *(const unsigned*)(mb + (size_t)f_l * NX + fn * 16) : 0u;
                unsigned nib = (w | (w >> 7) | (w >> 14) | (w >> 21)) & 0xFu;
                const int p = ft * 16 + fn * 4;
                mbits[p >> 5] |= nib << (p & 31);
            }
        }
    } else {
        const int* mi = (const int*)maskT + n0w + ksec * 4;
        #pragma unroll
        for (int ft = 0; ft < NFT; ++ft) {
            const int f_l = ft * 16 + fr;
            #pragma unroll
            for (int fn = 0; fn < 4; ++fn) {
                unsigned nib = 0u;
                if (f_l < NF) {
                    u32x4 v = *(const u32x4*)(mi + (size_t)f_l * NX + fn * 16);
                    nib = (v.x ? 1u : 0u) | (v.y ? 2u : 0u)
                        | (v.z ? 4u : 0u) | (v.w ? 8u : 0u);
                }
                const int p = ft * 16 + fn * 4;
                mbits[p >> 5] |= nib << (p & 31);
            }
        }
    }

    unsigned short (*ylds)[72] = (unsigned short (*)[72])smem[wv]; // 32x72 bf16
    float          (*ldsW)[68] = (float (*)[68])smem[wv];          // 16x68 f32

    // Prologue: load channel c0's Y strip into registers (before any store).
    u32x4 ycur[4];
    {
        const unsigned short* src = Abf + (size_t)c0 * NBASIS * NX + n0w;
        #pragma unroll
        for (int i = 0; i < 4; ++i) {
            int idx = lane + 64 * i;             // 0..255
            int row = idx >> 3, seg = idx & 7;
            ycur[i] = (u32x4)(0u, 0u, 0u, 0u);
            if (row < NBASIS)
                ycur[i] = *(const u32x4*)(src + (size_t)row * NX + seg * 8);
        }
    }

    __syncthreads();     // vtlds ready

    #pragma unroll 1
    for (int cc = 0; cc < CPB; ++cc) {
        const int c = c0 + cc;

        // Write staged Y regs to LDS (DS in-order; compiler keeps may-alias order).
        #pragma unroll
        for (int i = 0; i < 4; ++i) {
            int idx = lane + 64 * i;
            int row = idx >> 3, seg = idx & 7;
            *(u32x4*)&ylds[row][seg * 8] = ycur[i];
        }

        // Gather A-frags: yfrag[fn][j] = Y[k=ksec*8+j][n_local=fn*16+fr].
        bf16x8 yfrag[4];
        #pragma unroll
        for (int fn = 0; fn < 4; ++fn) {
            #pragma unroll
            for (int j = 0; j < 8; ++j)
                yfrag[fn][j] = (short)ylds[ksec * 8 + j][fn * 16 + fr];
        }

        // Issue next channel's Y loads BEFORE this channel's store stream.
        if (cc + 1 < CPB) {
            const unsigned short* src = Abf + (size_t)(c + 1) * NBASIS * NX + n0w;
            #pragma unroll
            for (int i = 0; i < 4; ++i) {
                int idx = lane + 64 * i;
                int row = idx >> 3, seg = idx & 7;
                u32x4 v = (u32x4)(0u, 0u, 0u, 0u);
                if (row < NBASIS)
                    v = *(const u32x4*)(src + (size_t)row * NX + seg * 8);
                ycur[i] = v;
            }
        }

        float* outc = out + (size_t)c * NF * NX;

        #pragma unroll
        for (int ft = 0; ft < NFT; ++ft) {
            bf16x8 vt = *(const bf16x8*)&vtlds[ft * 512 + lane * 8]; // lgkm only

            #pragma unroll
            for (int fn = 0; fn < 4; ++fn) {
                const int p = ft * 16 + fn * 4;
                const unsigned nib = (mbits[p >> 5] >> (p & 31)) & 0xFu;
                f32x4 d = __builtin_amdgcn_mfma_f32_16x16x32_bf16(
                    yfrag[fn], vt, (f32x4)(0.f, 0.f, 0.f, 0.f), 0, 0, 0);
                f32x4 o;
                #pragma unroll
                for (int r = 0; r < 4; ++r)
                    o[r] = (nib & (1u << r)) ? d[r] : 0.0f;
                *(f32x4*)&ldsW[fr][fn * 16 + ksec * 4] = o;
            }

            // f-major drain: NT stores, 256 B contiguous per 16-lane group.
            #pragma unroll
            for (int rl = 0; rl < 4; ++rl) {
                int f_local = rl * 4 + ksec;
                int f = ft * 16 + f_local;
                f32x4 v = *(const f32x4*)&ldsW[f_local][fr * 4];
                if (f < NF)
                    __builtin_nontemporal_store(v,
                        (f32x4*)(outc + (size_t)f * NX + n0w + fr * 4));
            }
        }
    }
}

extern "C" void kernel_launch(void* const* d_in, const int* in_sizes, int n_in,
                              void* d_out, int out_size, void* d_ws, size_t ws_size,
                              hipStream_t stream) {
    const float* x    = (const float*)d_in[0];   // (30,256,256,2) f32
    const float* csm  = (const float*)d_in[1];   // (8,256,256,2) f32
    const float* VT   = (const float*)d_in[2];   // (30,200) f32
    const void*  mask = d_in[3];                 // (200,131072) bool/int
    float* out = (float*)d_out;                  // (8,200,131072) f32

    char* ws = (char*)d_ws;
    unsigned short* Amid   = (unsigned short*)ws;                         // 62.9 MB
    unsigned short* Abf    = (unsigned short*)(ws + ((size_t)64 << 20));  // 62.9 MB
    unsigned short* VTfrag = (unsigned short*)(ws + ((size_t)128 << 20)); // 13.3 KB

    vt_prep_kernel<<<(NFT * 512 + 255) / 256, 256, 0, stream>>>(VT, VTfrag);
    fft_rows_kernel<<<NIMG * 64, 256, 0, stream>>>(x, csm, Amid);
    fft_cols_kernel<<<NIMG * 16, 256, 0, stream>>>(Amid, Abf);
    project_mfma_kernel<<<dim3(NX / 256, NCH / CPB), 256, 0, stream>>>(
        Abf, VTfrag, mask, out);
}